// Round 1
// 229.036 us; speedup vs baseline: 1.1666x; 1.1666x over previous
//
#include <hip/hip_runtime.h>

typedef _Float16 half8 __attribute__((ext_vector_type(8)));
typedef _Float16 half4 __attribute__((ext_vector_type(4)));
typedef float f32x4 __attribute__((ext_vector_type(4)));

#define TT 512
#define HH 64
#define MB 8      // real batches per block -> 256 blocks; cols 8..15 are broadcast dups
#define S  72     // state row stride (halfs): 144B rows, 16B-aligned b128 reads
#define XS 2056   // xbuf per-batch stride (halfs): 512*4 + 8 pad (pad also absorbs t=TT prefetch)

// lane l <- lane l^8 (within each 16-lane row), full-rate VALU DPP, no LDS
__device__ __forceinline__ float xor8(float v) {
    return __builtin_bit_cast(float,
        __builtin_amdgcn_update_dpp(0, __builtin_bit_cast(int, v),
                                    0x128 /* row_ror:8 == xor 8 in 16-rows */,
                                    0xF, 0xF, true));
}

__global__ __launch_bounds__(512, 1)
void lstm_v12(const float* __restrict__ x,
              const float* __restrict__ W_ih,
              const float* __restrict__ W_hh,
              const float* __restrict__ b_ih,
              const float* __restrict__ b_hh,
              const float* __restrict__ W_fc,
              const float* __restrict__ b_fc,
              float* __restrict__ out)
{
    __shared__ __align__(16) _Float16 st[2][8 * S];      // 2304 B: h state rows 0..7, dbuf
    __shared__ __align__(16) _Float16 xbuf[MB * XS];     // 32896 B: ALL x, staged once

    const int tid = threadIdx.x;
    const int w   = tid >> 6;      // wave 0..7
    const int l   = tid & 63;
    const int q   = l >> 4;
    const int col = l & 15;
    const int b0  = blockIdx.x * MB;
    const int xcol = col & 7;      // cols 8..15 broadcast a real batch
    const bool lo = (col < 8);

    const float kN = -1.4426950408889634f;   // -log2(e)
    const float kP =  2.8853900817779268f;   // +2*log2(e)

    // ---- persistent A fragments (weights), 2 tiles per wave ----
    // tile p of wave w covers gate-rows r(m) = 64*(m&3) + 8w + 2*(m>>2) + p
    // => lane (q,col) reg j = gate j of unit u = 8w + 2q + p
    // Weights PRESCALED by the sigmoid/tanh exp2 constants (f32 mul BEFORE f16
    // convert: same single rounding as unscaled) -> update uses exp2(gate) directly.
    half8 aw[2][3];
    #pragma unroll
    for (int p = 0; p < 2; ++p) {
        const int r = 64 * (col & 3) + 8 * w + 2 * (col >> 2) + p;
        const float scale = ((col & 3) == 2) ? kP : kN;   // gate g -> kP, i/f/o -> kN
        #pragma unroll
        for (int c = 0; c < 2; ++c) {
            const float* src = W_hh + r * HH + 32 * c + 8 * q;
            half8 v;
            #pragma unroll
            for (int j = 0; j < 8; ++j) v[j] = (_Float16)(src[j] * scale);
            aw[p][c] = v;
        }
        half8 v = {};
        if (q == 0) {   // k=64..67 -> W_ih, k=68 -> bias (B supplies 1.0 at k=68)
            #pragma unroll
            for (int j = 0; j < 4; ++j) v[j] = (_Float16)(W_ih[r * 4 + j] * scale);
            v[4] = (_Float16)((b_ih[r] + b_hh[r]) * scale);
        }
        aw[p][2] = v;
    }

    // ---- pre-stage ALL x for this block's 8 batches into LDS (f16) ----
    #pragma unroll
    for (int it = 0; it < (MB * TT) / 512; ++it) {
        const int task = tid + it * 512;
        const int b = task >> 9, t = task & 511;
        float4 v = *(const float4*)(x + ((size_t)(b0 + b) * TT + t) * 4);
        half4 hx;
        hx[0] = (_Float16)v.x; hx[1] = (_Float16)v.y;
        hx[2] = (_Float16)v.z; hx[3] = (_Float16)v.w;
        *(half4*)&xbuf[b * XS + t * 4] = hx;
    }

    // ---- zero h state (both buffers, rows 0..7) ----
    {
        _Float16* p0 = &st[0][0];
        for (int i = tid; i < 2 * 8 * S; i += 512) p0[i] = (_Float16)0.f;
    }
    __syncthreads();

    float cs = 0.f;                // cell state: unit 8w+2q+(col>>3), batch col&7
    const int wrow = xcol * S + 8 * w + 2 * q + (col >> 3);   // loop-invariant h-write addr
    const _Float16 hone = (_Float16)1.0f, hzer = (_Float16)0.f;
    const f32x4 z4 = {0.f, 0.f, 0.f, 0.f};

    // prologue: x/bias MFMA for t=0
    f32x4 accx0, accx1;
    {
        half4 xv = *(const half4*)&xbuf[xcol * XS + 0];
        half8 bx = {xv[0], xv[1], xv[2], xv[3], hone, hzer, hzer, hzer};
        accx0 = __builtin_amdgcn_mfma_f32_16x16x32_f16(aw[0][2], bx, z4, 0, 0, 0);
        accx1 = __builtin_amdgcn_mfma_f32_16x16x32_f16(aw[1][2], bx, z4, 0, 0, 0);
    }

    #pragma unroll 4
    for (int t = 0; t < TT; ++t) {
        const int rb = t & 1, wb = rb ^ 1;
        const _Float16* sr = &st[rb][0];

        // broadcast reads: dup cols read the same address as their real partner (free)
        half8 bh0 = *(const half8*)&sr[xcol * S +      8 * q];   // k 0..31
        half8 bh1 = *(const half8*)&sr[xcol * S + 32 + 8 * q];   // k 32..63
        half4 xv2 = *(const half4*)&xbuf[xcol * XS + (t + 1) * 4]; // prefetch (pad-safe at t=TT-1)

        // h-MFMAs: chain depth 2 (x/bias contribution was precomputed last iter)
        f32x4 a0 = __builtin_amdgcn_mfma_f32_16x16x32_f16(aw[0][0], bh0, accx0, 0, 0, 0);
        f32x4 a1 = __builtin_amdgcn_mfma_f32_16x16x32_f16(aw[1][0], bh0, accx1, 0, 0, 0);
        a0 = __builtin_amdgcn_mfma_f32_16x16x32_f16(aw[0][1], bh1, a0, 0, 0, 0);
        a1 = __builtin_amdgcn_mfma_f32_16x16x32_f16(aw[1][1], bh1, a1, 0, 0, 0);

        // x/bias MFMAs for t+1, independent of this step's h -> fills MFMA pipe
        {
            half8 bx2 = {xv2[0], xv2[1], xv2[2], xv2[3], hone, hzer, hzer, hzer};
            accx0 = __builtin_amdgcn_mfma_f32_16x16x32_f16(aw[0][2], bx2, z4, 0, 0, 0);
            accx1 = __builtin_amdgcn_mfma_f32_16x16x32_f16(aw[1][2], bx2, z4, 0, 0, 0);
        }

        // ---- redistribute: every lane does exactly ONE real cell update ----
        // low cols: unit 8w+2q+0 (acc0); high cols: unit 8w+2q+1 of batch col-8 (acc1 via DPP)
        const float s0 = xor8(a1[0]);
        const float s1 = xor8(a1[1]);
        const float s2 = xor8(a1[2]);
        const float s3 = xor8(a1[3]);
        const float gi = lo ? a0[0] : s0;   // prescaled by kN
        const float gf = lo ? a0[1] : s1;   // prescaled by kN
        const float gg = lo ? a0[2] : s2;   // prescaled by kP
        const float go = lo ? a0[3] : s3;   // prescaled by kN

        const float EI = __builtin_amdgcn_exp2f(gi);
        const float EF = __builtin_amdgcn_exp2f(gf);
        const float EG = __builtin_amdgcn_exp2f(gg);
        const float rF = __builtin_amdgcn_rcpf(1.f + EF);
        const float r1 = __builtin_amdgcn_rcpf((1.f + EI) * (EG + 1.f));
        cs = cs * rF + (EG - 1.f) * r1;
        const float EO = __builtin_amdgcn_exp2f(go);
        const float EC = __builtin_amdgcn_exp2f(kP * cs);
        const float r2 = __builtin_amdgcn_rcpf((1.f + EO) * (EC + 1.f));
        const float hn = (EC - 1.f) * r2;

        st[wb][wrow] = (_Float16)hn;    // 2B write; partner lanes hit other half of same dword
        __syncthreads();
    }

    // ---- FC epilogue: final h in st[0] (TT even) ----
    if (tid < MB * 4) {
        const int b = tid >> 2, o = tid & 3;
        float s = b_fc[o];
        const float* wf = W_fc + o * HH;
        #pragma unroll
        for (int k = 0; k < HH; ++k)
            s = fmaf((float)st[0][b * S + k], wf[k], s);
        out[(size_t)(b0 + b) * 4 + o] = s;
    }
}

extern "C" void kernel_launch(void* const* d_in, const int* in_sizes, int n_in,
                              void* d_out, int out_size, void* d_ws, size_t ws_size,
                              hipStream_t stream) {
    const float* x    = (const float*)d_in[0];
    const float* W_ih = (const float*)d_in[1];
    const float* W_hh = (const float*)d_in[2];
    const float* b_ih = (const float*)d_in[3];
    const float* b_hh = (const float*)d_in[4];
    const float* W_fc = (const float*)d_in[5];
    const float* b_fc = (const float*)d_in[6];
    float* out = (float*)d_out;
    lstm_v12<<<2048 / MB, 512, 0, stream>>>(x, W_ih, W_hh, b_ih, b_hh, W_fc, b_fc, out);
}